// Round 1
// baseline (685.076 us; speedup 1.0000x reference)
//
#include <hip/hip_runtime.h>
#include <cstdint>
#include <cstddef>

typedef unsigned short u16;
typedef __attribute__((ext_vector_type(8))) short bf16x8;
typedef __attribute__((ext_vector_type(4))) float f32x4;

__device__ __forceinline__ u16 f2b(float f) {
  union { float f; unsigned u; } v; v.f = f;
  unsigned u = v.u;
  return (u16)((u + 0x7fffu + ((u >> 16) & 1u)) >> 16);
}
__device__ __forceinline__ float b2f(u16 h) {
  union { unsigned u; float f; } v; v.u = ((unsigned)h) << 16;
  return v.f;
}

// async global->LDS, 16B per lane. LDS dest must be wave-uniform base + lane*16.
__device__ __forceinline__ void g2l16(const void* g, void* l) {
  __builtin_amdgcn_global_load_lds((__attribute__((address_space(1))) void*)(g),
                                   (__attribute__((address_space(3))) void*)(l), 16, 0, 0);
}

// ---------------- fp32 -> bf16 cast (vectorized x4) ----------------
__global__ __launch_bounds__(256) void cast_f2b_v4(const float* __restrict__ in,
                                                   u16* __restrict__ out, int n4) {
  int i = blockIdx.x * 256 + threadIdx.x;
  if (i >= n4) return;
  float4 v = ((const float4*)in)[i];
  ushort4 r;
  r.x = f2b(v.x); r.y = f2b(v.y); r.z = f2b(v.z); r.w = f2b(v.w);
  ((ushort4*)out)[i] = r;
}

// ---------------- C = A @ B^T   (A: MxK bf16, B: NxK bf16, both K-major) ------
// m97 structure: 128x128 tile, BK=64, 4 waves (2x2), 4x4 16x16x32 MFMA per wave.
template <bool BF16_OUT>
__global__ __launch_bounds__(256) void gemm_bt(const u16* __restrict__ A,
                                               const u16* __restrict__ B,
                                               void* __restrict__ C, int N, int K) {
  __shared__ u16 As[128 * 64];
  __shared__ u16 Bs[128 * 64];
  const int tid = threadIdx.x;
  const int wid = tid >> 6;
  const int lane = tid & 63;
  const int lm = lane & 15;
  const int quad = lane >> 4;
  const int wm = (wid & 1) * 64;
  const int wn = (wid >> 1) * 64;
  const int bm = blockIdx.y * 128;
  const int bn = blockIdx.x * 128;

  const u16* Ab = A + (size_t)bm * K;
  const u16* Bb = B + (size_t)bn * K;

  f32x4 zero = {0.f, 0.f, 0.f, 0.f};
  f32x4 acc[4][4];
#pragma unroll
  for (int i = 0; i < 4; ++i)
#pragma unroll
    for (int j = 0; j < 4; ++j) acc[i][j] = zero;

  for (int k0 = 0; k0 < K; k0 += 64) {
#pragma unroll
    for (int it = 0; it < 4; ++it) {
      int c = it * 256 + tid;
      int row = c >> 3;
      int cg = (c & 7) * 8;
      g2l16(Ab + (size_t)row * K + k0 + cg, As + c * 8);
      g2l16(Bb + (size_t)row * K + k0 + cg, Bs + c * 8);
    }
    __syncthreads();
#pragma unroll
    for (int ks = 0; ks < 2; ++ks) {
      bf16x8 a[4], b[4];
#pragma unroll
      for (int i = 0; i < 4; ++i)
        a[i] = *(const bf16x8*)(As + (wm + i * 16 + lm) * 64 + ks * 32 + quad * 8);
#pragma unroll
      for (int j = 0; j < 4; ++j)
        b[j] = *(const bf16x8*)(Bs + (wn + j * 16 + lm) * 64 + ks * 32 + quad * 8);
#pragma unroll
      for (int i = 0; i < 4; ++i)
#pragma unroll
        for (int j = 0; j < 4; ++j)
          acc[i][j] = __builtin_amdgcn_mfma_f32_16x16x32_bf16(a[i], b[j], acc[i][j], 0, 0, 0);
    }
    __syncthreads();
  }

#pragma unroll
  for (int i = 0; i < 4; ++i)
#pragma unroll
    for (int j = 0; j < 4; ++j)
#pragma unroll
      for (int r = 0; r < 4; ++r) {
        int row = bm + wm + i * 16 + quad * 4 + r;
        int col = bn + wn + j * 16 + lm;
        float v = acc[i][j][r];
        if (BF16_OUT)
          ((u16*)C)[(size_t)row * N + col] = f2b(v);
        else
          ((float*)C)[(size_t)row * N + col] = v;
      }
}

// ---------------- RoPE + head rearrange ----------------
// Y: (B*S, 6144) cols = [q_sem(1024) | k_sem(1024) | q_geo(1024) | k_geo(1024) | v(2048)]
// Q,K: (B*H, S, 128)   VT: (B*H, 128, S)
__global__ __launch_bounds__(256) void rope_rearrange(const u16* __restrict__ Y,
                                                      u16* __restrict__ Q,
                                                      u16* __restrict__ Kb,
                                                      u16* __restrict__ VT) {
  const int idx = blockIdx.x * 256 + threadIdx.x;  // over B*S*2048
  const int c = idx & 2047;
  const int bs = idx >> 11;
  const int s = bs & 2047;
  const int h = c >> 7;
  const int d = c & 127;
  const u16* Yr = Y + (size_t)bs * 6144;
  const size_t bh = (size_t)(bs >> 11) * 16 + h;

  // V (transposed store)
  VT[(bh * 128 + d) * 2048 + s] = Yr[4096 + c];

  float qv, kv;
  if (d < 64) {
    qv = b2f(Yr[h * 64 + d]);
    kv = b2f(Yr[1024 + h * 64 + d]);
  } else {
    int dg = d - 64;
    int f0 = dg & 31;
    float inv = __powf(10000.0f, -(float)(2 * f0) * (1.0f / 64.0f));
    float ang = (float)s * inv;
    float sn = sinf(ang), cs = cosf(ang);
    float qx1 = b2f(Yr[2048 + h * 64 + f0]);
    float qx2 = b2f(Yr[2048 + h * 64 + f0 + 32]);
    float kx1 = b2f(Yr[3072 + h * 64 + f0]);
    float kx2 = b2f(Yr[3072 + h * 64 + f0 + 32]);
    if (dg < 32) { qv = qx1 * cs - qx2 * sn; kv = kx1 * cs - kx2 * sn; }
    else         { qv = qx1 * sn + qx2 * cs; kv = kx1 * sn + kx2 * cs; }
  }
  size_t qo = (bh * 2048 + s) * 128 + d;
  Q[qo] = f2b(qv);
  Kb[qo] = f2b(kv);
}

// ---------------- fused causal attention (flash-style) ----------------
// per block: one (b,h) and one 64-row Q tile. 4 waves; wave w owns rows 16w..16w+15.
__global__ __launch_bounds__(256) void attn_fused(const u16* __restrict__ Q,
                                                  const u16* __restrict__ K,
                                                  const u16* __restrict__ VT,
                                                  u16* __restrict__ O) {
  constexpr int S = 2048;
  constexpr int D = 128;
  __shared__ u16 Qs[64 * 128];
  __shared__ u16 Ks[64 * 128];
  __shared__ u16 Vs[128 * 64];  // VT tile: [d][s_local]
  __shared__ u16 Ps[64 * 64];
  const int qt = blockIdx.x;
  const int bh = blockIdx.y;
  const int b = bh >> 4, h = bh & 15;
  const int tid = threadIdx.x, wid = tid >> 6, lane = tid & 63;
  const int lm = lane & 15, quad = lane >> 4;
  const int wrow = wid * 16;

  const u16* Qb = Q + ((size_t)bh * S + (size_t)qt * 64) * D;
#pragma unroll
  for (int it = 0; it < 4; ++it) { int c = it * 256 + tid; g2l16(Qb + c * 8, Qs + c * 8); }

  float m_r[4] = {-1e30f, -1e30f, -1e30f, -1e30f};
  float l_r[4] = {0.f, 0.f, 0.f, 0.f};
  f32x4 zero = {0.f, 0.f, 0.f, 0.f};
  f32x4 oacc[8];
#pragma unroll
  for (int t = 0; t < 8; ++t) oacc[t] = zero;

  const float scale = 0.0883883476483184f;  // 1/sqrt(128)

  for (int kt = 0; kt <= qt; ++kt) {
    __syncthreads();  // protect Ks/Vs/Ps from prior iteration's readers
    const u16* Kt = K + ((size_t)bh * S + (size_t)kt * 64) * D;
#pragma unroll
    for (int it = 0; it < 4; ++it) { int c = it * 256 + tid; g2l16(Kt + c * 8, Ks + c * 8); }
    const u16* Vt = VT + (size_t)bh * D * S + (size_t)kt * 64;
#pragma unroll
    for (int it = 0; it < 4; ++it) {
      int c = it * 256 + tid;
      g2l16(Vt + (size_t)(c >> 3) * S + (c & 7) * 8, Vs + c * 8);
    }
    __syncthreads();

    // S-tile = Q K^T : wave rows wrow..wrow+15, 64 cols
    f32x4 sc[4];
#pragma unroll
    for (int j = 0; j < 4; ++j) sc[j] = zero;
#pragma unroll
    for (int ks = 0; ks < 4; ++ks) {
      bf16x8 aq = *(const bf16x8*)(Qs + (wrow + lm) * 128 + ks * 32 + quad * 8);
#pragma unroll
      for (int j = 0; j < 4; ++j) {
        bf16x8 bk = *(const bf16x8*)(Ks + (j * 16 + lm) * 128 + ks * 32 + quad * 8);
        sc[j] = __builtin_amdgcn_mfma_f32_16x16x32_bf16(aq, bk, sc[j], 0, 0, 0);
      }
    }

    const bool diag = (kt == qt);
#pragma unroll
    for (int r = 0; r < 4; ++r) {
      float pv[4];
#pragma unroll
      for (int j = 0; j < 4; ++j) pv[j] = sc[j][r] * scale;
      if (diag) {
        const int qcol = wrow + quad * 4 + r;  // row within this 64-tile
#pragma unroll
        for (int j = 0; j < 4; ++j)
          if (j * 16 + lm > qcol) pv[j] = -1e30f;
      }
      float mx = fmaxf(fmaxf(pv[0], pv[1]), fmaxf(pv[2], pv[3]));
#pragma unroll
      for (int dd = 1; dd < 16; dd <<= 1) mx = fmaxf(mx, __shfl_xor(mx, dd));
      float mnew = fmaxf(m_r[r], mx);
      float alpha = __expf(m_r[r] - mnew);
      float rs = 0.f;
#pragma unroll
      for (int j = 0; j < 4; ++j) { pv[j] = __expf(pv[j] - mnew); rs += pv[j]; }
#pragma unroll
      for (int dd = 1; dd < 16; dd <<= 1) rs += __shfl_xor(rs, dd);
      l_r[r] = l_r[r] * alpha + rs;
      m_r[r] = mnew;
#pragma unroll
      for (int t = 0; t < 8; ++t) oacc[t][r] *= alpha;
      const int prow = (wrow + quad * 4 + r) * 64;
#pragma unroll
      for (int j = 0; j < 4; ++j) Ps[prow + j * 16 + lm] = f2b(pv[j]);
    }
    __syncthreads();  // P visible to all waves

    // O += P @ V : P (64x64) as A, Vs ([d][s]) as B
#pragma unroll
    for (int ks = 0; ks < 2; ++ks) {
      bf16x8 ap = *(const bf16x8*)(Ps + (wrow + lm) * 64 + ks * 32 + quad * 8);
#pragma unroll
      for (int t = 0; t < 8; ++t) {
        bf16x8 bv = *(const bf16x8*)(Vs + (t * 16 + lm) * 64 + ks * 32 + quad * 8);
        oacc[t] = __builtin_amdgcn_mfma_f32_16x16x32_bf16(ap, bv, oacc[t], 0, 0, 0);
      }
    }
  }

  // epilogue: O row = b*S + s, col = h*128 + d  (bf16)
#pragma unroll
  for (int r = 0; r < 4; ++r) {
    float inv = 1.0f / l_r[r];
    const int srow = qt * 64 + wrow + quad * 4 + r;
    u16* Orow = O + ((size_t)b * S + srow) * 2048 + h * 128;
#pragma unroll
    for (int t = 0; t < 8; ++t) Orow[t * 16 + lm] = f2b(oacc[t][r] * inv);
  }
}

extern "C" void kernel_launch(void* const* d_in, const int* in_sizes, int n_in,
                              void* d_out, int out_size, void* d_ws, size_t ws_size,
                              hipStream_t stream) {
  const float* x      = (const float*)d_in[0];
  const float* Wq_sem = (const float*)d_in[1];
  const float* Wk_sem = (const float*)d_in[2];
  const float* Wq_geo = (const float*)d_in[3];
  const float* Wk_geo = (const float*)d_in[4];
  const float* Wv     = (const float*)d_in[5];
  const float* Wo     = (const float*)d_in[6];

  char* ws = (char*)d_ws;
  // layout (bytes):
  //   [0, 16M)          xb  (x bf16, 4096x2048)        -> later reused as Q
  //   [16M, 41.2M)      Wall (6144x2048 bf16)          -> later reused as O
  //   [41.2M, 49.6M)    Wob  (2048x2048 bf16)
  //   [49.6M, 99.9M)    Y    (4096x6144 bf16)
  // d_out (33.5MB) used as scratch for K (16.7M) + VT (16.7M) until final GEMM.
  u16* xb   = (u16*)(ws);
  u16* Wall = (u16*)(ws + 16777216);
  u16* Wob  = (u16*)(ws + 16777216 + 25165824);
  u16* Y    = (u16*)(ws + 16777216 + 25165824 + 8388608);
  u16* Qb   = xb;
  u16* Ob   = Wall;
  u16* Kb   = (u16*)d_out;
  u16* VT   = (u16*)((char*)d_out + 16777216);

  // casts to bf16
  cast_f2b_v4<<<8192, 256, 0, stream>>>(x, xb, 2097152);
  cast_f2b_v4<<<2048, 256, 0, stream>>>(Wq_sem, Wall + 0 * 2097152, 524288);
  cast_f2b_v4<<<2048, 256, 0, stream>>>(Wk_sem, Wall + 1 * 2097152, 524288);
  cast_f2b_v4<<<2048, 256, 0, stream>>>(Wq_geo, Wall + 2 * 2097152, 524288);
  cast_f2b_v4<<<2048, 256, 0, stream>>>(Wk_geo, Wall + 3 * 2097152, 524288);
  cast_f2b_v4<<<4096, 256, 0, stream>>>(Wv,     Wall + 4 * 2097152, 1048576);
  cast_f2b_v4<<<4096, 256, 0, stream>>>(Wo, Wob, 1048576);

  // fused QKV projection: Y = x @ Wall^T   (M=4096, N=6144, K=2048)
  gemm_bt<true><<<dim3(48, 32), 256, 0, stream>>>(xb, Wall, Y, 6144, 2048);

  // RoPE + head split/rearrange
  rope_rearrange<<<32768, 256, 0, stream>>>(Y, Qb, Kb, VT);

  // causal flash attention -> O (B*S, 2048) bf16
  attn_fused<<<dim3(32, 32), 256, 0, stream>>>(Qb, Kb, VT, Ob);

  // final projection: out = O @ Wo^T  (M=4096, N=2048, K=2048), fp32 out
  gemm_bt<false><<<dim3(16, 32), 256, 0, stream>>>(Ob, Wob, d_out, 2048, 2048);
}

// Round 5
// 528.812 us; speedup vs baseline: 1.2955x; 1.2955x over previous
//
#include <hip/hip_runtime.h>
#include <cstdint>
#include <cstddef>

typedef unsigned short u16;
typedef __attribute__((ext_vector_type(8))) short bf16x8;
typedef __attribute__((ext_vector_type(4))) float f32x4;

#define MFMA32(a, b, c) __builtin_amdgcn_mfma_f32_16x16x32_bf16(a, b, c, 0, 0, 0)

__device__ __forceinline__ u16 f2b(float f) {
  union { float f; unsigned u; } v; v.f = f;
  unsigned u = v.u;
  return (u16)((u + 0x7fffu + ((u >> 16) & 1u)) >> 16);
}
__device__ __forceinline__ float b2f(u16 h) {
  union { unsigned u; float f; } v; v.u = ((unsigned)h) << 16;
  return v.f;
}

// async global->LDS, 16B per lane. LDS dest must be wave-uniform base + lane*16.
__device__ __forceinline__ void g2l16(const void* g, void* l) {
  __builtin_amdgcn_global_load_lds((__attribute__((address_space(1))) void*)(g),
                                   (__attribute__((address_space(3))) void*)(l), 16, 0, 0);
}

// ---------------- fp32 -> bf16 cast (vectorized x4) ----------------
__global__ __launch_bounds__(256) void cast_f2b_v4(const float* __restrict__ in,
                                                   u16* __restrict__ out, int n4) {
  int i = blockIdx.x * 256 + threadIdx.x;
  if (i >= n4) return;
  float4 v = ((const float4*)in)[i];
  ushort4 r;
  r.x = f2b(v.x); r.y = f2b(v.y); r.z = f2b(v.z); r.w = f2b(v.w);
  ((ushort4*)out)[i] = r;
}

// ---------------- C = A @ B^T   (A: MxK bf16, B: NxK bf16, both K-major) ------
// R1-proven m97 structure: 128x128 tile, BK=64, 4 waves (2x2), 4x4 MFMA/wave.
template <bool BF16_OUT>
__global__ __launch_bounds__(256) void gemm_bt(const u16* __restrict__ A,
                                               const u16* __restrict__ B,
                                               void* __restrict__ C, int N, int K) {
  __shared__ u16 As[128 * 64];
  __shared__ u16 Bs[128 * 64];
  const int tid = threadIdx.x;
  const int wid = tid >> 6;
  const int lane = tid & 63;
  const int lm = lane & 15;
  const int quad = lane >> 4;
  const int wm = (wid & 1) * 64;
  const int wn = (wid >> 1) * 64;
  const int bm = blockIdx.y * 128;
  const int bn = blockIdx.x * 128;

  const u16* Ab = A + (size_t)bm * K;
  const u16* Bb = B + (size_t)bn * K;

  f32x4 zero = {0.f, 0.f, 0.f, 0.f};
  f32x4 acc[4][4];
#pragma unroll
  for (int i = 0; i < 4; ++i)
#pragma unroll
    for (int j = 0; j < 4; ++j) acc[i][j] = zero;

  for (int k0 = 0; k0 < K; k0 += 64) {
#pragma unroll
    for (int it = 0; it < 4; ++it) {
      int c = it * 256 + tid;
      int row = c >> 3;
      int cg = (c & 7) * 8;
      g2l16(Ab + (size_t)row * K + k0 + cg, As + c * 8);
      g2l16(Bb + (size_t)row * K + k0 + cg, Bs + c * 8);
    }
    __syncthreads();
#pragma unroll
    for (int ks = 0; ks < 2; ++ks) {
      bf16x8 a[4], b[4];
#pragma unroll
      for (int i = 0; i < 4; ++i)
        a[i] = *(const bf16x8*)(As + (wm + i * 16 + lm) * 64 + ks * 32 + quad * 8);
#pragma unroll
      for (int j = 0; j < 4; ++j)
        b[j] = *(const bf16x8*)(Bs + (wn + j * 16 + lm) * 64 + ks * 32 + quad * 8);
#pragma unroll
      for (int i = 0; i < 4; ++i)
#pragma unroll
        for (int j = 0; j < 4; ++j)
          acc[i][j] = MFMA32(a[i], b[j], acc[i][j]);
    }
    __syncthreads();
  }

#pragma unroll
  for (int i = 0; i < 4; ++i)
#pragma unroll
    for (int j = 0; j < 4; ++j)
#pragma unroll
      for (int r = 0; r < 4; ++r) {
        int row = bm + wm + i * 16 + quad * 4 + r;
        int col = bn + wn + j * 16 + lm;
        float v = acc[i][j][r];
        if (BF16_OUT)
          ((u16*)C)[(size_t)row * N + col] = f2b(v);
        else
          ((float*)C)[(size_t)row * N + col] = v;
      }
}

// ---------------- RoPE + head rearrange (R1-proven, + Q pre-scale) ------------
// Y: (B*S, 6144) cols = [q_sem(1024) | k_sem(1024) | q_geo(1024) | k_geo(1024) | v(2048)]
// Q,K: (B*H, S, 128)   VT: (B*H, 128, S).  Q scaled by (1/sqrt(128))*log2(e).
__global__ __launch_bounds__(256) void rope_rearrange(const u16* __restrict__ Y,
                                                      u16* __restrict__ Q,
                                                      u16* __restrict__ Kb,
                                                      u16* __restrict__ VT) {
  const float SC = 0.12751744f;  // (1/sqrt(128)) * log2(e)
  const int idx = blockIdx.x * 256 + threadIdx.x;  // over B*S*2048
  const int c = idx & 2047;
  const int bs = idx >> 11;
  const int s = bs & 2047;
  const int h = c >> 7;
  const int d = c & 127;
  const u16* Yr = Y + (size_t)bs * 6144;
  const size_t bh = (size_t)(bs >> 11) * 16 + h;

  // V (transposed store)
  VT[(bh * 128 + d) * 2048 + s] = Yr[4096 + c];

  float qv, kv;
  if (d < 64) {
    qv = b2f(Yr[h * 64 + d]);
    kv = b2f(Yr[1024 + h * 64 + d]);
  } else {
    int dg = d - 64;
    int f0 = dg & 31;
    float inv = __powf(10000.0f, -(float)(2 * f0) * (1.0f / 64.0f));
    float ang = (float)s * inv;
    float sn = sinf(ang), cs = cosf(ang);
    float qx1 = b2f(Yr[2048 + h * 64 + f0]);
    float qx2 = b2f(Yr[2048 + h * 64 + f0 + 32]);
    float kx1 = b2f(Yr[3072 + h * 64 + f0]);
    float kx2 = b2f(Yr[3072 + h * 64 + f0 + 32]);
    if (dg < 32) { qv = qx1 * cs - qx2 * sn; kv = kx1 * cs - kx2 * sn; }
    else         { qv = qx1 * sn + qx2 * cs; kv = kx1 * sn + kx2 * cs; }
  }
  size_t qo = (bh * 2048 + s) * 128 + d;
  Q[qo] = f2b(qv * SC);
  Kb[qo] = f2b(kv);
}

// ---------------- fused causal attention v4 (R1 dataflow, 4 audited deltas) ---
// vs R1-passed attn_fused: (1) no-running-max softmax (Q pre-scaled, exp2, clamp
// 30); (2) Q fragments in registers instead of Qs LDS (same values); (3) Ps row
// stride 64 -> 72 (pad; plain stores so g2l constraint doesn't apply); (4) two
// q-tiles per block (qt = bx, 31-bx) for uniform work. Ks/Vs staging, all
// fragment reads, barriers (3/step), and epilogue identical to R1.
__global__ __launch_bounds__(256, 3) void attn_v4(const u16* __restrict__ Q,
                                                  const u16* __restrict__ K,
                                                  const u16* __restrict__ VT,
                                                  u16* __restrict__ O) {
  constexpr int S = 2048;
  constexpr int D = 128;
  __shared__ u16 Ks[64 * 128];
  __shared__ u16 Vs[128 * 64];  // VT tile: [d][s_local]
  __shared__ u16 Ps[64 * 72];   // padded stride 72 (144B rows, 16B-aligned)
  const int bx = blockIdx.x;
  const int bh = blockIdx.y;
  const int b = bh >> 4, h = bh & 15;
  const int tid = threadIdx.x, wid = tid >> 6, lane = tid & 63;
  const int lm = lane & 15, quad = lane >> 4;
  const int wrow = wid * 16;

#pragma unroll 1
  for (int pass = 0; pass < 2; ++pass) {
    const int qt = pass == 0 ? bx : 31 - bx;

    // Q A-operand fragments direct from global (same values R1 read from Qs)
    bf16x8 aq[4];
#pragma unroll
    for (int ks = 0; ks < 4; ++ks)
      aq[ks] = *(const bf16x8*)(Q + ((size_t)bh * S + (size_t)qt * 64 + wrow + lm) * D +
                                ks * 32 + quad * 8);

    float l_r[4] = {0.f, 0.f, 0.f, 0.f};
    f32x4 zero = {0.f, 0.f, 0.f, 0.f};
    f32x4 oacc[8];
#pragma unroll
    for (int t = 0; t < 8; ++t) oacc[t] = zero;

    for (int kt = 0; kt <= qt; ++kt) {
      __syncthreads();  // protect Ks/Vs/Ps from prior iteration's readers
      const u16* Kt = K + ((size_t)bh * S + (size_t)kt * 64) * D;
#pragma unroll
      for (int it = 0; it < 4; ++it) { int c = it * 256 + tid; g2l16(Kt + c * 8, Ks + c * 8); }
      const u16* Vt = VT + (size_t)bh * D * S + (size_t)kt * 64;
#pragma unroll
      for (int it = 0; it < 4; ++it) {
        int c = it * 256 + tid;
        g2l16(Vt + (size_t)(c >> 3) * S + (c & 7) * 8, Vs + c * 8);
      }
      __syncthreads();

      // S-tile = Q K^T : wave rows wrow..wrow+15, 64 cols
      f32x4 sc[4];
#pragma unroll
      for (int j = 0; j < 4; ++j) sc[j] = zero;
#pragma unroll
      for (int ks = 0; ks < 4; ++ks) {
#pragma unroll
        for (int j = 0; j < 4; ++j) {
          bf16x8 bk = *(const bf16x8*)(Ks + (j * 16 + lm) * 128 + ks * 32 + quad * 8);
          sc[j] = MFMA32(aq[ks], bk, sc[j]);
        }
      }

      const bool diag = (kt == qt);
#pragma unroll
      for (int r = 0; r < 4; ++r) {
        const int qcol = wrow + quad * 4 + r;  // q row within this 64-tile
        float pv[4];
        float rs = 0.f;
#pragma unroll
        for (int j = 0; j < 4; ++j) {
          float p = __builtin_amdgcn_exp2f(fminf(sc[j][r], 30.0f));
          if (diag && (j * 16 + lm > qcol)) p = 0.f;
          rs += p;
          pv[j] = p;
        }
#pragma unroll
        for (int dd = 1; dd < 16; dd <<= 1) rs += __shfl_xor(rs, dd);
        l_r[r] += rs;
        const int prow = (wrow + quad * 4 + r) * 72;
#pragma unroll
        for (int j = 0; j < 4; ++j) Ps[prow + j * 16 + lm] = f2b(pv[j]);
      }
      __syncthreads();  // P visible to all waves

      // O += P @ V : P (64x64, stride 72) as A, Vs ([d][s]) as B
#pragma unroll
      for (int ks = 0; ks < 2; ++ks) {
        bf16x8 ap = *(const bf16x8*)(Ps + (wrow + lm) * 72 + ks * 32 + quad * 8);
#pragma unroll
        for (int t = 0; t < 8; ++t) {
          bf16x8 bv = *(const bf16x8*)(Vs + (t * 16 + lm) * 64 + ks * 32 + quad * 8);
          oacc[t] = MFMA32(ap, bv, oacc[t]);
        }
      }
    }

    // epilogue: O row = b*S + s, col = h*128 + d  (bf16)
#pragma unroll
    for (int r = 0; r < 4; ++r) {
      float inv = 1.0f / l_r[r];
      const int srow = qt * 64 + wrow + quad * 4 + r;
      u16* Orow = O + ((size_t)b * S + srow) * 2048 + h * 128;
#pragma unroll
      for (int t = 0; t < 8; ++t) Orow[t * 16 + lm] = f2b(oacc[t][r] * inv);
    }
  }
}

extern "C" void kernel_launch(void* const* d_in, const int* in_sizes, int n_in,
                              void* d_out, int out_size, void* d_ws, size_t ws_size,
                              hipStream_t stream) {
  const float* x      = (const float*)d_in[0];
  const float* Wq_sem = (const float*)d_in[1];
  const float* Wk_sem = (const float*)d_in[2];
  const float* Wq_geo = (const float*)d_in[3];
  const float* Wk_geo = (const float*)d_in[4];
  const float* Wv     = (const float*)d_in[5];
  const float* Wo     = (const float*)d_in[6];

  char* ws = (char*)d_ws;
  // layout (bytes):
  //   [0, 16M)          xb  (x bf16, 4096x2048)        -> later reused as Q
  //   [16M, 41.2M)      Wall (6144x2048 bf16)          -> later reused as O
  //   [41.2M, 49.6M)    Wob  (2048x2048 bf16)
  //   [49.6M, 99.9M)    Y    (4096x6144 bf16)
  // d_out (33.5MB) used as scratch for K (16.7M) + VT (16.7M) until final GEMM.
  u16* xb   = (u16*)(ws);
  u16* Wall = (u16*)(ws + 16777216);
  u16* Wob  = (u16*)(ws + 16777216 + 25165824);
  u16* Y    = (u16*)(ws + 16777216 + 25165824 + 8388608);
  u16* Qb   = xb;
  u16* Ob   = Wall;
  u16* Kb   = (u16*)d_out;
  u16* VT   = (u16*)((char*)d_out + 16777216);

  // casts to bf16
  cast_f2b_v4<<<8192, 256, 0, stream>>>(x, xb, 2097152);
  cast_f2b_v4<<<2048, 256, 0, stream>>>(Wq_sem, Wall + 0 * 2097152, 524288);
  cast_f2b_v4<<<2048, 256, 0, stream>>>(Wk_sem, Wall + 1 * 2097152, 524288);
  cast_f2b_v4<<<2048, 256, 0, stream>>>(Wq_geo, Wall + 2 * 2097152, 524288);
  cast_f2b_v4<<<2048, 256, 0, stream>>>(Wk_geo, Wall + 3 * 2097152, 524288);
  cast_f2b_v4<<<4096, 256, 0, stream>>>(Wv,     Wall + 4 * 2097152, 1048576);
  cast_f2b_v4<<<4096, 256, 0, stream>>>(Wo, Wob, 1048576);

  // fused QKV projection: Y = x @ Wall^T   (M=4096, N=6144, K=2048)
  gemm_bt<true><<<dim3(48, 32), 256, 0, stream>>>(xb, Wall, Y, 6144, 2048);

  // RoPE + head split/rearrange (Q pre-scaled by 1/sqrt(128)*log2e)
  rope_rearrange<<<32768, 256, 0, stream>>>(Y, Qb, Kb, VT);

  // causal flash attention -> O (B*S, 2048) bf16
  attn_v4<<<dim3(16, 32), 256, 0, stream>>>(Qb, Kb, VT, Ob);

  // final projection: out = O @ Wo^T  (M=4096, N=2048, K=2048), fp32 out
  gemm_bt<false><<<dim3(16, 32), 256, 0, stream>>>(Ob, Wob, d_out, 2048, 2048);
}

// Round 6
// 477.490 us; speedup vs baseline: 1.4347x; 1.1075x over previous
//
#include <hip/hip_runtime.h>
#include <cstdint>
#include <cstddef>

typedef unsigned short u16;
typedef __attribute__((ext_vector_type(8))) short bf16x8;
typedef __attribute__((ext_vector_type(4))) float f32x4;

#define MFMA32(a, b, c) __builtin_amdgcn_mfma_f32_16x16x32_bf16(a, b, c, 0, 0, 0)

__device__ __forceinline__ u16 f2b(float f) {
  union { float f; unsigned u; } v; v.f = f;
  unsigned u = v.u;
  return (u16)((u + 0x7fffu + ((u >> 16) & 1u)) >> 16);
}
__device__ __forceinline__ float b2f(u16 h) {
  union { unsigned u; float f; } v; v.u = ((unsigned)h) << 16;
  return v.f;
}

// async global->LDS, 16B per lane. LDS dest must be wave-uniform base + lane*16.
__device__ __forceinline__ void g2l16(const void* g, void* l) {
  __builtin_amdgcn_global_load_lds((__attribute__((address_space(1))) void*)(g),
                                   (__attribute__((address_space(3))) void*)(l), 16, 0, 0);
}

// ---------------- fp32 -> bf16 cast (vectorized x4) ----------------
__global__ __launch_bounds__(256) void cast_f2b_v4(const float* __restrict__ in,
                                                   u16* __restrict__ out, int n4) {
  int i = blockIdx.x * 256 + threadIdx.x;
  if (i >= n4) return;
  float4 v = ((const float4*)in)[i];
  ushort4 r;
  r.x = f2b(v.x); r.y = f2b(v.y); r.z = f2b(v.z); r.w = f2b(v.w);
  ((ushort4*)out)[i] = r;
}

// ---------------- C = A @ B^T   (A: MxK bf16, B: NxK bf16, both K-major) ------
// 128x128 tile, BK=64, 4 waves (2x2), 4x4 MFMA/wave.
// LDS XOR-swizzled chunk-major: chunk(row,kc) stored at linear chunk index
//   (row>>3)*64 + (row&7)*8 + (kc ^ (row&7))
// -> each b128 fragment read spreads over all 8 bank-groups (8-phase, optimal)
// instead of 16-way same-group serialization with the plain row-major layout.
template <bool BF16_OUT>
__global__ __launch_bounds__(256) void gemm_bt(const u16* __restrict__ A,
                                               const u16* __restrict__ B,
                                               void* __restrict__ C, int N, int K) {
  __shared__ u16 As[128 * 64];
  __shared__ u16 Bs[128 * 64];
  const int tid = threadIdx.x;
  const int wid = tid >> 6;
  const int lane = tid & 63;
  const int lm = lane & 15;
  const int quad = lane >> 4;
  const int r3 = lm & 7;
  const int wm = (wid & 1) * 64;
  const int wn = (wid >> 1) * 64;
  const int bm = blockIdx.y * 128;
  const int bn = blockIdx.x * 128;

  const u16* Ab = A + (size_t)bm * K;
  const u16* Bb = B + (size_t)bn * K;

  f32x4 zero = {0.f, 0.f, 0.f, 0.f};
  f32x4 acc[4][4];
#pragma unroll
  for (int i = 0; i < 4; ++i)
#pragma unroll
    for (int j = 0; j < 4; ++j) acc[i][j] = zero;

  for (int k0 = 0; k0 < K; k0 += 64) {
#pragma unroll
    for (int it = 0; it < 4; ++it) {
      int c = it * 256 + tid;
      int rg = c >> 6, rw = (c >> 3) & 7, u = c & 7;
      int row = rg * 8 + rw;
      int chd = u ^ rw;  // store chunk (row, chd) at linear chunk c
      g2l16(Ab + (size_t)row * K + k0 + chd * 8, As + c * 8);
      g2l16(Bb + (size_t)row * K + k0 + chd * 8, Bs + c * 8);
    }
    __syncthreads();
#pragma unroll
    for (int ks = 0; ks < 2; ++ks) {
      bf16x8 a[4], b[4];
      int chd = ks * 4 + quad;
#pragma unroll
      for (int i = 0; i < 4; ++i) {
        int row = wm + i * 16 + lm;  // row&7 == r3
        a[i] = *(const bf16x8*)(As + (((row >> 3) * 64 + r3 * 8 + (chd ^ r3)) * 8));
      }
#pragma unroll
      for (int j = 0; j < 4; ++j) {
        int row = wn + j * 16 + lm;
        b[j] = *(const bf16x8*)(Bs + (((row >> 3) * 64 + r3 * 8 + (chd ^ r3)) * 8));
      }
#pragma unroll
      for (int i = 0; i < 4; ++i)
#pragma unroll
        for (int j = 0; j < 4; ++j)
          acc[i][j] = MFMA32(a[i], b[j], acc[i][j]);
    }
    __syncthreads();
  }

#pragma unroll
  for (int i = 0; i < 4; ++i)
#pragma unroll
    for (int j = 0; j < 4; ++j)
#pragma unroll
      for (int r = 0; r < 4; ++r) {
        int row = bm + wm + i * 16 + quad * 4 + r;
        int col = bn + wn + j * 16 + lm;
        float v = acc[i][j][r];
        if (BF16_OUT)
          ((u16*)C)[(size_t)row * N + col] = f2b(v);
        else
          ((float*)C)[(size_t)row * N + col] = v;
      }
}

// ---------------- RoPE + head rearrange (R1-proven, + Q pre-scale) ------------
// Y: (B*S, 6144) cols = [q_sem(1024) | k_sem(1024) | q_geo(1024) | k_geo(1024) | v(2048)]
// Q,K: (B*H, S, 128)   VT: (B*H, 128, S).  Q scaled by (1/sqrt(128))*log2(e).
__global__ __launch_bounds__(256) void rope_rearrange(const u16* __restrict__ Y,
                                                      u16* __restrict__ Q,
                                                      u16* __restrict__ Kb,
                                                      u16* __restrict__ VT) {
  const float SC = 0.12751744f;  // (1/sqrt(128)) * log2(e)
  const int idx = blockIdx.x * 256 + threadIdx.x;  // over B*S*2048
  const int c = idx & 2047;
  const int bs = idx >> 11;
  const int s = bs & 2047;
  const int h = c >> 7;
  const int d = c & 127;
  const u16* Yr = Y + (size_t)bs * 6144;
  const size_t bh = (size_t)(bs >> 11) * 16 + h;

  // V (transposed store)
  VT[(bh * 128 + d) * 2048 + s] = Yr[4096 + c];

  float qv, kv;
  if (d < 64) {
    qv = b2f(Yr[h * 64 + d]);
    kv = b2f(Yr[1024 + h * 64 + d]);
  } else {
    int dg = d - 64;
    int f0 = dg & 31;
    float inv = __powf(10000.0f, -(float)(2 * f0) * (1.0f / 64.0f));
    float ang = (float)s * inv;
    float sn = sinf(ang), cs = cosf(ang);
    float qx1 = b2f(Yr[2048 + h * 64 + f0]);
    float qx2 = b2f(Yr[2048 + h * 64 + f0 + 32]);
    float kx1 = b2f(Yr[3072 + h * 64 + f0]);
    float kx2 = b2f(Yr[3072 + h * 64 + f0 + 32]);
    if (dg < 32) { qv = qx1 * cs - qx2 * sn; kv = kx1 * cs - kx2 * sn; }
    else         { qv = qx1 * sn + qx2 * cs; kv = kx1 * sn + kx2 * cs; }
  }
  size_t qo = (bh * 2048 + s) * 128 + d;
  Q[qo] = f2b(qv * SC);
  Kb[qo] = f2b(kv);
}

// ---------------- fused causal attention v4 (R5-passed, unchanged) ------------
__global__ __launch_bounds__(256, 3) void attn_v4(const u16* __restrict__ Q,
                                                  const u16* __restrict__ K,
                                                  const u16* __restrict__ VT,
                                                  u16* __restrict__ O) {
  constexpr int S = 2048;
  constexpr int D = 128;
  __shared__ u16 Ks[64 * 128];
  __shared__ u16 Vs[128 * 64];  // VT tile: [d][s_local]
  __shared__ u16 Ps[64 * 72];   // padded stride 72 (144B rows, 16B-aligned)
  const int bx = blockIdx.x;
  const int bh = blockIdx.y;
  const int b = bh >> 4, h = bh & 15;
  const int tid = threadIdx.x, wid = tid >> 6, lane = tid & 63;
  const int lm = lane & 15, quad = lane >> 4;
  const int wrow = wid * 16;

#pragma unroll 1
  for (int pass = 0; pass < 2; ++pass) {
    const int qt = pass == 0 ? bx : 31 - bx;

    // Q A-operand fragments direct from global
    bf16x8 aq[4];
#pragma unroll
    for (int ks = 0; ks < 4; ++ks)
      aq[ks] = *(const bf16x8*)(Q + ((size_t)bh * S + (size_t)qt * 64 + wrow + lm) * D +
                                ks * 32 + quad * 8);

    float l_r[4] = {0.f, 0.f, 0.f, 0.f};
    f32x4 zero = {0.f, 0.f, 0.f, 0.f};
    f32x4 oacc[8];
#pragma unroll
    for (int t = 0; t < 8; ++t) oacc[t] = zero;

    for (int kt = 0; kt <= qt; ++kt) {
      __syncthreads();  // protect Ks/Vs/Ps from prior iteration's readers
      const u16* Kt = K + ((size_t)bh * S + (size_t)kt * 64) * D;
#pragma unroll
      for (int it = 0; it < 4; ++it) { int c = it * 256 + tid; g2l16(Kt + c * 8, Ks + c * 8); }
      const u16* Vt = VT + (size_t)bh * D * S + (size_t)kt * 64;
#pragma unroll
      for (int it = 0; it < 4; ++it) {
        int c = it * 256 + tid;
        g2l16(Vt + (size_t)(c >> 3) * S + (c & 7) * 8, Vs + c * 8);
      }
      __syncthreads();

      // S-tile = Q K^T : wave rows wrow..wrow+15, 64 cols
      f32x4 sc[4];
#pragma unroll
      for (int j = 0; j < 4; ++j) sc[j] = zero;
#pragma unroll
      for (int ks = 0; ks < 4; ++ks) {
#pragma unroll
        for (int j = 0; j < 4; ++j) {
          bf16x8 bk = *(const bf16x8*)(Ks + (j * 16 + lm) * 128 + ks * 32 + quad * 8);
          sc[j] = MFMA32(aq[ks], bk, sc[j]);
        }
      }

      const bool diag = (kt == qt);
#pragma unroll
      for (int r = 0; r < 4; ++r) {
        const int qcol = wrow + quad * 4 + r;  // q row within this 64-tile
        float pv[4];
        float rs = 0.f;
#pragma unroll
        for (int j = 0; j < 4; ++j) {
          float p = __builtin_amdgcn_exp2f(fminf(sc[j][r], 30.0f));
          if (diag && (j * 16 + lm > qcol)) p = 0.f;
          rs += p;
          pv[j] = p;
        }
#pragma unroll
        for (int dd = 1; dd < 16; dd <<= 1) rs += __shfl_xor(rs, dd);
        l_r[r] += rs;
        const int prow = (wrow + quad * 4 + r) * 72;
#pragma unroll
        for (int j = 0; j < 4; ++j) Ps[prow + j * 16 + lm] = f2b(pv[j]);
      }
      __syncthreads();  // P visible to all waves

      // O += P @ V : P (64x64, stride 72) as A, Vs ([d][s]) as B
#pragma unroll
      for (int ks = 0; ks < 2; ++ks) {
        bf16x8 ap = *(const bf16x8*)(Ps + (wrow + lm) * 72 + ks * 32 + quad * 8);
#pragma unroll
        for (int t = 0; t < 8; ++t) {
          bf16x8 bv = *(const bf16x8*)(Vs + (t * 16 + lm) * 64 + ks * 32 + quad * 8);
          oacc[t] = MFMA32(ap, bv, oacc[t]);
        }
      }
    }

    // epilogue: O row = b*S + s, col = h*128 + d  (bf16)
#pragma unroll
    for (int r = 0; r < 4; ++r) {
      float inv = 1.0f / l_r[r];
      const int srow = qt * 64 + wrow + quad * 4 + r;
      u16* Orow = O + ((size_t)b * S + srow) * 2048 + h * 128;
#pragma unroll
      for (int t = 0; t < 8; ++t) Orow[t * 16 + lm] = f2b(oacc[t][r] * inv);
    }
  }
}

extern "C" void kernel_launch(void* const* d_in, const int* in_sizes, int n_in,
                              void* d_out, int out_size, void* d_ws, size_t ws_size,
                              hipStream_t stream) {
  const float* x      = (const float*)d_in[0];
  const float* Wq_sem = (const float*)d_in[1];
  const float* Wk_sem = (const float*)d_in[2];
  const float* Wq_geo = (const float*)d_in[3];
  const float* Wk_geo = (const float*)d_in[4];
  const float* Wv     = (const float*)d_in[5];
  const float* Wo     = (const float*)d_in[6];

  char* ws = (char*)d_ws;
  // layout (bytes):
  //   [0, 16M)          xb  (x bf16, 4096x2048)        -> later reused as Q
  //   [16M, 41.2M)      Wall (6144x2048 bf16)          -> later reused as O
  //   [41.2M, 49.6M)    Wob  (2048x2048 bf16)
  //   [49.6M, 99.9M)    Y    (4096x6144 bf16)
  // d_out (33.5MB) used as scratch for K (16.7M) + VT (16.7M) until final GEMM.
  u16* xb   = (u16*)(ws);
  u16* Wall = (u16*)(ws + 16777216);
  u16* Wob  = (u16*)(ws + 16777216 + 25165824);
  u16* Y    = (u16*)(ws + 16777216 + 25165824 + 8388608);
  u16* Qb   = xb;
  u16* Ob   = Wall;
  u16* Kb   = (u16*)d_out;
  u16* VT   = (u16*)((char*)d_out + 16777216);

  // casts to bf16
  cast_f2b_v4<<<8192, 256, 0, stream>>>(x, xb, 2097152);
  cast_f2b_v4<<<2048, 256, 0, stream>>>(Wq_sem, Wall + 0 * 2097152, 524288);
  cast_f2b_v4<<<2048, 256, 0, stream>>>(Wk_sem, Wall + 1 * 2097152, 524288);
  cast_f2b_v4<<<2048, 256, 0, stream>>>(Wq_geo, Wall + 2 * 2097152, 524288);
  cast_f2b_v4<<<2048, 256, 0, stream>>>(Wk_geo, Wall + 3 * 2097152, 524288);
  cast_f2b_v4<<<4096, 256, 0, stream>>>(Wv,     Wall + 4 * 2097152, 1048576);
  cast_f2b_v4<<<4096, 256, 0, stream>>>(Wo, Wob, 1048576);

  // fused QKV projection: Y = x @ Wall^T   (M=4096, N=6144, K=2048)
  gemm_bt<true><<<dim3(48, 32), 256, 0, stream>>>(xb, Wall, Y, 6144, 2048);

  // RoPE + head split/rearrange (Q pre-scaled by 1/sqrt(128)*log2e)
  rope_rearrange<<<32768, 256, 0, stream>>>(Y, Qb, Kb, VT);

  // causal flash attention -> O (B*S, 2048) bf16
  attn_v4<<<dim3(16, 32), 256, 0, stream>>>(Qb, Kb, VT, Ob);

  // final projection: out = O @ Wo^T  (M=4096, N=2048, K=2048), fp32 out
  gemm_bt<false><<<dim3(16, 32), 256, 0, stream>>>(Ob, Wob, d_out, 2048, 2048);
}